// Round 10
// baseline (337.060 us; speedup 1.0000x reference)
//
#include <hip/hip_runtime.h>
#include <math.h>

#define BB 4
#define SS 2048
#define HH 256
#define DD 64
#define NLAYERS 2
#define NPART 256     // i-partials for column stats (128 chunks x 2 halves)

// static scales for f16 hi/lo splits (layer-2 activations are large)
#define XSC  (1.f/64.f)   // x stored as x/64
#define XSCI 64.f
#define FSC  (1.f/256.f)  // ft stored as ft/256
#define WSC  256.f        // W stored as 256*W (256 * 1/256 = 1 in product)
#define LNWSC 5.5451774444795624f   // ln(256)

typedef _Float16 f16;
typedef f16 half8 __attribute__((ext_vector_type(8)));
typedef f16 half4 __attribute__((ext_vector_type(4)));
typedef float f32x4 __attribute__((ext_vector_type(4)));
#define MFMA16(a, b, c) __builtin_amdgcn_mfma_f32_16x16x32_f16(a, b, c, 0, 0, 0)

__device__ __forceinline__ float lrelu(float v) { return v > 0.f ? v : 0.01f * v; }
__device__ __forceinline__ int enc(float f) { int i = __float_as_int(f); return i >= 0 ? i : (i ^ 0x7fffffff); }
__device__ __forceinline__ float dec(int k) { int i = k >= 0 ? k : (k ^ 0x7fffffff); return __int_as_float(i); }
__device__ __forceinline__ void split8(const float* v, half8& h, half8& l) {
    #pragma unroll
    for (int e = 0; e < 8; ++e) {
        f16 hh = (f16)v[e]; h[e] = hh; l[e] = (f16)((v[e] - (float)hh) * 2048.f);
    }
}

// blocks 0-127: Wy = gc_w@attn_w^T split, by, w1/w2 splits, FMX init
// blocks 128-1151: inputs*XSC -> xh/xl split
__global__ __launch_bounds__(256) void prep_all(
    const float* __restrict__ gc_w, const float* __restrict__ gc_b,
    const float* __restrict__ attn_w,
    f16* __restrict__ WysH, f16* __restrict__ WysL, float* __restrict__ by,
    const float* __restrict__ w1, const float* __restrict__ w2,
    f16* __restrict__ w1h, f16* __restrict__ w1l,
    f16* __restrict__ w2h, f16* __restrict__ w2l, int* __restrict__ FMXi,
    const float* __restrict__ inputs, f16* __restrict__ xh, f16* __restrict__ xl)
{
    if (blockIdx.x >= 128) {
        long i = ((long)(blockIdx.x - 128) * 256 + threadIdx.x) * 8;
        float4 a = *(const float4*)&inputs[i];
        float4 b = *(const float4*)&inputs[i + 4];
        float v[8] = {a.x * XSC, a.y * XSC, a.z * XSC, a.w * XSC,
                      b.x * XSC, b.y * XSC, b.z * XSC, b.w * XSC};
        half8 h, l; split8(v, h, l);
        *(half8*)&xh[i] = h; *(half8*)&xl[i] = l;
        return;
    }
    int L = blockIdx.x >> 6, d = blockIdx.x & 63;
    int h = threadIdx.x;
    const float* gwr = gc_w + (long)L * HH * HH + (long)h * HH;
    const float* aw = attn_w + (long)L * DD * HH + (long)d * HH;
    float acc = 0.f;
    #pragma unroll 4
    for (int hp = 0; hp < HH; hp += 4) {
        float4 g4 = *(const float4*)&gwr[hp];
        float4 a4 = *(const float4*)&aw[hp];
        acc += g4.x * a4.x + g4.y * a4.y + g4.z * a4.z + g4.w * a4.w;
    }
    f16 hh = (f16)acc;
    WysH[((long)L * DD + d) * HH + h] = hh;
    WysL[((long)L * DD + d) * HH + h] = (f16)((acc - (float)hh) * 2048.f);
    if (h == 0) {
        float ba = 0.f;
        const float* gb = gc_b + (long)L * HH;
        for (int hp = 0; hp < HH; ++hp) ba += gb[hp] * aw[hp];
        by[L * DD + d] = ba;
    }
    int gt = blockIdx.x * 256 + h;   // 32768 threads x 4 = 131072 = 2*65536
    #pragma unroll
    for (int p = 0; p < 4; ++p) {
        int e = gt * 4 + p;
        if (e < 65536) {
            float v = w1[e]; f16 x = (f16)v;
            w1h[e] = x; w1l[e] = (f16)((v - (float)x) * 2048.f);
        } else {
            int e2 = e - 65536;
            float v = w2[e2]; f16 x = (f16)v;
            w2h[e2] = x; w2l[e2] = (f16)((v - (float)x) * 2048.f);
        }
    }
    if (blockIdx.x == 0 && h < 2 * BB) FMXi[h] = enc(-1e30f);
}

// yT[b][d][s] (split of y/64) = (x/64) @ Wy  (4 waves/block, wave = 16 rows)
__global__ __launch_bounds__(256) void y_mfma(
    const f16* __restrict__ xh, const f16* __restrict__ xl,
    const f16* __restrict__ WyhL, const f16* __restrict__ WylL,
    f16* __restrict__ yTh, f16* __restrict__ yTl)
{
    const int tid = threadIdx.x;
    const int w = tid >> 6, l = tid & 63;
    const int gw = blockIdx.x * 4 + w;   // global wave: b*128 + st
    const int b = gw >> 7, st = gw & 127;
    const int s0 = st * 16;
    const int lr = l & 15, kg = (l >> 4) * 8;
    const f16* Aph = xh + ((long)b * SS + s0 + lr) * HH;
    const f16* Apl = xl + ((long)b * SS + s0 + lr) * HH;
    f32x4 acch[4] = {}, accm[4] = {};
    #pragma unroll
    for (int k0 = 0; k0 < HH; k0 += 32) {
        half8 ah = *(const half8*)(Aph + k0 + kg);
        half8 al = *(const half8*)(Apl + k0 + kg);
        #pragma unroll
        for (int dt = 0; dt < 4; ++dt) {
            long boff = (long)(dt * 16 + lr) * HH + k0 + kg;
            half8 bh = *(const half8*)(WyhL + boff);
            half8 bl = *(const half8*)(WylL + boff);
            acch[dt] = MFMA16(ah, bh, acch[dt]);
            accm[dt] = MFMA16(ah, bl, accm[dt]);
            accm[dt] = MFMA16(al, bh, accm[dt]);
        }
    }
    const int rg0 = (l >> 4) * 4;
    #pragma unroll
    for (int dt = 0; dt < 4; ++dt) {
        int d = dt * 16 + lr;
        half4 h4, l4;
        #pragma unroll
        for (int rr = 0; rr < 4; ++rr) {
            float v = acch[dt][rr] + accm[dt][rr] * (1.f / 2048.f);
            f16 hh = (f16)v; h4[rr] = hh; l4[rr] = (f16)((v - (float)hh) * 2048.f);
        }
        long ob = ((long)b * DD + d) * SS + s0 + rg0;
        *(half4*)(yTh + ob) = h4;
        *(half4*)(yTl + ob) = l4;
    }
}

// ft tile [16 x 64] = adj[i0..i0+16, :] @ y  (8 waves x 256-k, adj prefetched)
// epilogue: F = ft@attn_a, atomic fmax, fT split write.
__global__ __launch_bounds__(512, 2) void ftp_fused(
    const float* __restrict__ adjB,
    const f16* __restrict__ yTh, const f16* __restrict__ yTl,
    const float* __restrict__ byL, const float* __restrict__ aaL,
    float* __restrict__ F, f16* __restrict__ fTh, f16* __restrict__ fTl,
    int* __restrict__ fmxSlot)
{
    __shared__ float Ls[8][16][68];
    __shared__ float fmaxS[16];
    const int b = blockIdx.y;
    const int i0 = blockIdx.x * 16;
    const int tid = threadIdx.x;
    const int w = tid >> 6, l = tid & 63, lr = l & 15, kg = (l >> 4) * 8;
    const float* Arow = adjB + (long)b * 2 * SS * SS + (long)(i0 + lr) * SS;
    const f16* Bh = yTh + ((long)b * DD + lr) * SS;
    const f16* Bl = yTl + ((long)b * DD + lr) * SS;

    f32x4 acch[4] = {}, accm[4] = {};
    float4 a0 = *(const float4*)(Arow + w * 256 + kg);
    float4 a1 = *(const float4*)(Arow + w * 256 + kg + 4);
    #pragma unroll
    for (int ks = 0; ks < 256; ks += 32) {
        float4 c0 = a0, c1 = a1;
        if (ks < 224) {   // prefetch next chunk (compile-time branch)
            int nk = w * 256 + ks + 32 + kg;
            a0 = *(const float4*)(Arow + nk);
            a1 = *(const float4*)(Arow + nk + 4);
        }
        int k = w * 256 + ks + kg;
        float av[8] = {c0.x, c0.y, c0.z, c0.w, c1.x, c1.y, c1.z, c1.w};
        half8 ah, al; split8(av, ah, al);
        #pragma unroll
        for (int dt = 0; dt < 4; ++dt) {
            long off = (long)dt * 16 * SS + k;
            half8 bh = *(const half8*)(Bh + off);
            half8 bl = *(const half8*)(Bl + off);
            acch[dt] = MFMA16(ah, bh, acch[dt]);
            accm[dt] = MFMA16(ah, bl, accm[dt]);
            accm[dt] = MFMA16(al, bh, accm[dt]);
        }
    }
    const int rg0 = (l >> 4) * 4;
    #pragma unroll
    for (int dt = 0; dt < 4; ++dt)
        #pragma unroll
        for (int rr = 0; rr < 4; ++rr)
            Ls[w][rg0 + rr][dt * 16 + lr] = acch[dt][rr] + accm[dt][rr] * (1.f / 2048.f);
    __syncthreads();

    // 8-way cross-wave reduce (x64 rescale + by), F-dot, fmax
    {
        int r = tid >> 5, q = tid & 31, c0 = q * 2;
        float s0 = 0.f, s1 = 0.f;
        #pragma unroll
        for (int ww = 0; ww < 8; ++ww) { s0 += Ls[ww][r][c0]; s1 += Ls[ww][r][c0 + 1]; }
        s0 = s0 * XSCI + byL[c0];
        s1 = s1 * XSCI + byL[c0 + 1];
        Ls[0][r][c0] = s0; Ls[0][r][c0 + 1] = s1;
        float dot = s0 * aaL[c0] + s1 * aaL[c0 + 1];
        dot += __shfl_xor(dot, 1, 64);
        dot += __shfl_xor(dot, 2, 64);
        dot += __shfl_xor(dot, 4, 64);
        dot += __shfl_xor(dot, 8, 64);
        dot += __shfl_xor(dot, 16, 64);
        if (q == 0) { F[b * SS + i0 + r] = dot; fmaxS[r] = dot; }
    }
    __syncthreads();
    if (tid == 0) {
        float m = -1e30f;
        #pragma unroll
        for (int r = 0; r < 16; ++r) m = fmaxf(m, fmaxS[r]);
        atomicMax(fmxSlot + b, enc(m));
    }
    // transposed split write of ft*FSC (first 256 threads)
    if (tid < 256) {
        int d = tid >> 2, sq = (tid & 3) * 4;
        half4 h4, l4;
        #pragma unroll
        for (int e = 0; e < 4; ++e) {
            float v = Ls[0][sq + e][d] * FSC;
            f16 hh = (f16)v; h4[e] = hh; l4[e] = (f16)((v - (float)hh) * 2048.f);
        }
        long ob = ((long)b * DD + d) * SS + i0 + sq;
        *(half4*)(fTh + ob) = h4;
        *(half4*)(fTl + ob) = l4;
    }
}

// Column softmax partial sums, bound M_j = lrelu(fmax_b + f_j) + 8.
// grid (2,128,BB) x 512 thr = 4 blocks/CU (32 waves/CU). Chunk = 16 rows,
// half = 8 rows, thread = 4 j. Fully unrolled 4 iters -> 8 float4 in flight.
__global__ __launch_bounds__(512) void col_stats_part(
    const float* __restrict__ biasb, const float* __restrict__ f,
    const int* __restrict__ fmxSlot,
    float* __restrict__ partS, float* __restrict__ Mv)
{
    __shared__ float fs[16];
    const int b = blockIdx.z;
    const int chunk = blockIdx.y;          // 0..127, 16 rows each
    const int half = threadIdx.x >> 8;     // 0/1 -> 8 rows each
    const int t = threadIdx.x & 255;
    const int j0 = blockIdx.x * 1024 + t * 4;
    const float* bb = biasb + (long)b * 2 * SS * SS;
    const int ibase = chunk * 16 + half * 8;

    if (threadIdx.x < 16) fs[threadIdx.x] = f[b * SS + chunk * 16 + threadIdx.x];

    float fj[4], M[4], s[4] = {0.f, 0.f, 0.f, 0.f};
    const float fmx = dec(fmxSlot[b]);
    #pragma unroll
    for (int q = 0; q < 4; ++q) {
        fj[q] = f[b * SS + j0 + q];
        M[q] = lrelu(fmx + fj[q]) + 8.f;
    }
    __syncthreads();

    #pragma unroll
    for (int ii = 0; ii < 8; ii += 2) {
        float fi0 = fs[half * 8 + ii], fi1 = fs[half * 8 + ii + 1];
        float4 b0 = *(const float4*)&bb[(long)(ibase + ii) * SS + j0];
        float4 b1 = *(const float4*)&bb[(long)(ibase + ii + 1) * SS + j0];
        s[0] += __expf(lrelu(fi0 + fj[0]) + b0.x - M[0]);
        s[1] += __expf(lrelu(fi0 + fj[1]) + b0.y - M[1]);
        s[2] += __expf(lrelu(fi0 + fj[2]) + b0.z - M[2]);
        s[3] += __expf(lrelu(fi0 + fj[3]) + b0.w - M[3]);
        s[0] += __expf(lrelu(fi1 + fj[0]) + b1.x - M[0]);
        s[1] += __expf(lrelu(fi1 + fj[1]) + b1.y - M[1]);
        s[2] += __expf(lrelu(fi1 + fj[2]) + b1.z - M[2]);
        s[3] += __expf(lrelu(fi1 + fj[3]) + b1.w - M[3]);
    }
    const int c = chunk * 2 + half;        // 0..255
    #pragma unroll
    for (int q = 0; q < 4; ++q)
        partS[((long)c * BB + b) * SS + j0 + q] = s[q];
    if (c == 0) {
        #pragma unroll
        for (int q = 0; q < 4; ++q) Mv[b * SS + j0 + q] = M[q];
    }
}

// FC[b,j] = (f_j, ln(WSC) - ln(sum_c partS) - M_j)  packed float2 stream
__global__ __launch_bounds__(256) void col_stats_merge(
    const float* __restrict__ partS, const float* __restrict__ Mv,
    const float* __restrict__ f, float2* __restrict__ FC)
{
    __shared__ float red[4][64];
    const int b = blockIdx.y;
    const int jl = threadIdx.x & 63;
    const int p = threadIdx.x >> 6;
    const int j = blockIdx.x * 64 + jl;
    float s = 0.f;
    #pragma unroll
    for (int k = 0; k < 64; ++k)
        s += partS[((long)(p * 64 + k) * BB + b) * SS + j];
    red[p][jl] = s;
    __syncthreads();
    if (p == 0) {
        float tot = ((red[0][jl] + red[1][jl]) + (red[2][jl] + red[3][jl]));
        float2 fc;
        fc.x = f[b * SS + j];
        fc.y = LNWSC - __logf(tot) - Mv[b * SS + j];
        FC[b * SS + j] = fc;
    }
}

// ret tile [16 x 64] = coefs[i0..i0+16, :] @ ft (8 waves x 256-j, bias prefetched)
// W*WSC = exp(lrelu(fi+fj) + bias + Cj). Epilogue: lrelu + tile + residual.
__global__ __launch_bounds__(512, 2) void pvp_fused(
    const float* __restrict__ biasb, const float* __restrict__ f,
    const float2* __restrict__ FC,
    const f16* __restrict__ fTh, const f16* __restrict__ fTl,
    const float* __restrict__ xin, float* __restrict__ X,
    f16* __restrict__ xh, f16* __restrict__ xl, int writeSplit)
{
    __shared__ float Ls[8][16][68];
    const int b = blockIdx.y;
    const int i0 = blockIdx.x * 16;
    const int tid = threadIdx.x;
    const int w = tid >> 6, l = tid & 63, lr = l & 15, kg = (l >> 4) * 8;
    const int irow = i0 + lr;
    const float fi = f[b * SS + irow];
    const float* brow = biasb + (long)b * 2 * SS * SS + (long)irow * SS;
    const float2* fcb = FC + (long)b * SS;
    const f16* Bh = fTh + ((long)b * DD + lr) * SS;
    const f16* Bl = fTl + ((long)b * DD + lr) * SS;

    f32x4 acch[4] = {}, accm[4] = {};
    float4 pb0 = *(const float4*)(brow + w * 256 + kg);
    float4 pb1 = *(const float4*)(brow + w * 256 + kg + 4);
    #pragma unroll
    for (int jc = 0; jc < 256; jc += 32) {
        float4 bs0 = pb0, bs1 = pb1;
        if (jc < 224) {   // prefetch next bias chunk (compile-time branch)
            int nj = w * 256 + jc + 32 + kg;
            pb0 = *(const float4*)(brow + nj);
            pb1 = *(const float4*)(brow + nj + 4);
        }
        const int jb = w * 256 + jc + kg;
        float4 fc0 = *(const float4*)&fcb[jb];       // (f,C) j, j+1
        float4 fc1 = *(const float4*)&fcb[jb + 2];
        float4 fc2 = *(const float4*)&fcb[jb + 4];
        float4 fc3 = *(const float4*)&fcb[jb + 6];
        float wv[8];
        wv[0] = __expf(lrelu(fi + fc0.x) + bs0.x + fc0.y);
        wv[1] = __expf(lrelu(fi + fc0.z) + bs0.y + fc0.w);
        wv[2] = __expf(lrelu(fi + fc1.x) + bs0.z + fc1.y);
        wv[3] = __expf(lrelu(fi + fc1.z) + bs0.w + fc1.w);
        wv[4] = __expf(lrelu(fi + fc2.x) + bs1.x + fc2.y);
        wv[5] = __expf(lrelu(fi + fc2.z) + bs1.y + fc2.w);
        wv[6] = __expf(lrelu(fi + fc3.x) + bs1.z + fc3.y);
        wv[7] = __expf(lrelu(fi + fc3.z) + bs1.w + fc3.w);
        half8 ah, al; split8(wv, ah, al);
        #pragma unroll
        for (int dt = 0; dt < 4; ++dt) {
            long off = (long)dt * 16 * SS + jb;
            half8 bh = *(const half8*)(Bh + off);
            half8 bl = *(const half8*)(Bl + off);
            acch[dt] = MFMA16(ah, bh, acch[dt]);
            accm[dt] = MFMA16(ah, bl, accm[dt]);
            accm[dt] = MFMA16(al, bh, accm[dt]);
        }
    }
    const int rg0 = (l >> 4) * 4;
    #pragma unroll
    for (int dt = 0; dt < 4; ++dt)
        #pragma unroll
        for (int rr = 0; rr < 4; ++rr)
            Ls[w][rg0 + rr][dt * 16 + lr] = acch[dt][rr] + accm[dt][rr] * (1.f / 2048.f);
    __syncthreads();

    // combine epilogue: v = lrelu(8-way sum), tile x4 + residual
    {
        int r = tid >> 5, q = tid & 31, dq = q * 2;
        float v0 = 0.f, v1 = 0.f;
        #pragma unroll
        for (int ww = 0; ww < 8; ++ww) { v0 += Ls[ww][r][dq]; v1 += Ls[ww][r][dq + 1]; }
        v0 = lrelu(v0); v1 = lrelu(v1);
        long rowoff = ((long)b * SS + i0 + r) * HH;
        #pragma unroll
        for (int rep = 0; rep < 4; ++rep) {
            long off = rowoff + rep * DD + dq;
            float o0 = v0 + xin[off];
            float o1 = v1 + xin[off + 1];
            X[off] = o0; X[off + 1] = o1;
            if (writeSplit) {
                float s0 = o0 * XSC, s1 = o1 * XSC;
                f16 h0 = (f16)s0, h1 = (f16)s1;
                xh[off] = h0; xl[off] = (f16)((s0 - (float)h0) * 2048.f);
                xh[off + 1] = h1; xl[off + 1] = (f16)((s1 - (float)h1) * 2048.f);
            }
        }
    }
}

// g = ln_a*(x-mean)/(std+eps) + ln_b + x0 ; wave-per-row, float4 per lane
__global__ __launch_bounds__(256) void layernorm_g(
    const float* __restrict__ x, const float* __restrict__ x0,
    const float* __restrict__ lna, const float* __restrict__ lnb,
    float* __restrict__ g, f16* __restrict__ gh, f16* __restrict__ gl)
{
    const int wave = threadIdx.x >> 6, lane = threadIdx.x & 63;
    const long row = (long)blockIdx.x * 4 + wave;
    const int c0 = lane * 4;
    float4 v = *(const float4*)&x[row * HH + c0];
    float s = v.x + v.y + v.z + v.w;
    #pragma unroll
    for (int off = 32; off; off >>= 1) s += __shfl_xor(s, off, 64);
    float mean = s * (1.f / HH);
    float dx = v.x - mean, dy = v.y - mean, dz = v.z - mean, dw = v.w - mean;
    float sq = dx * dx + dy * dy + dz * dz + dw * dw;
    #pragma unroll
    for (int off = 32; off; off >>= 1) sq += __shfl_xor(sq, off, 64);
    float stdv = sqrtf(sq * (1.f / (HH - 1)));
    float rinv = 1.f / (stdv + 1e-6f);
    float4 la = *(const float4*)&lna[c0];
    float4 lb = *(const float4*)&lnb[c0];
    float4 xo = *(const float4*)&x0[row * HH + c0];
    float gv[4];
    gv[0] = la.x * dx * rinv + lb.x + xo.x;
    gv[1] = la.y * dy * rinv + lb.y + xo.y;
    gv[2] = la.z * dz * rinv + lb.z + xo.z;
    gv[3] = la.w * dw * rinv + lb.w + xo.w;
    *(float4*)&g[row * HH + c0] = *(float4*)gv;
    half4 h4, l4;
    #pragma unroll
    for (int e = 0; e < 4; ++e) {
        f16 hh = (f16)gv[e]; h4[e] = hh; l4[e] = (f16)((gv[e] - (float)hh) * 2048.f);
    }
    *(half4*)&gh[row * HH + c0] = h4;
    *(half4*)&gl[row * HH + c0] = l4;
}

// C = A@B^T (+bias)(relu)(+res). A split [M][256]; B split [256][256] (row=n).
__global__ __launch_bounds__(256) void ffn_mfma(
    const f16* __restrict__ Ah, const f16* __restrict__ Al,
    const f16* __restrict__ Bh, const f16* __restrict__ Bl,
    const float* __restrict__ bias, const float* __restrict__ res,
    float* __restrict__ outF, f16* __restrict__ outH, f16* __restrict__ outL,
    int doRelu)
{
    __shared__ float Ls[64][68];
    const int i0 = blockIdx.x * 64, j0 = blockIdx.y * 64;
    const int tid = threadIdx.x;
    const int w = tid >> 6, l = tid & 63, lr = l & 15, kg = (l >> 4) * 8;
    const f16* Aph = Ah + ((long)i0 + w * 16 + lr) * HH;
    const f16* Apl = Al + ((long)i0 + w * 16 + lr) * HH;
    f32x4 acch[4] = {}, accm[4] = {};
    #pragma unroll
    for (int k0 = 0; k0 < HH; k0 += 32) {
        half8 ah = *(const half8*)(Aph + k0 + kg);
        half8 al = *(const half8*)(Apl + k0 + kg);
        #pragma unroll
        for (int dt = 0; dt < 4; ++dt) {
            long boff = ((long)(j0 + dt * 16 + lr)) * HH + k0 + kg;
            half8 bh = *(const half8*)(Bh + boff);
            half8 bl = *(const half8*)(Bl + boff);
            acch[dt] = MFMA16(ah, bh, acch[dt]);
            accm[dt] = MFMA16(ah, bl, accm[dt]);
            accm[dt] = MFMA16(al, bh, accm[dt]);
        }
    }
    const int rg0 = (l >> 4) * 4;
    #pragma unroll
    for (int dt = 0; dt < 4; ++dt) {
        float bj = bias[j0 + dt * 16 + lr];
        #pragma unroll
        for (int rr = 0; rr < 4; ++rr) {
            float v = acch[dt][rr] + accm[dt][rr] * (1.f / 2048.f) + bj;
            if (doRelu) v = fmaxf(v, 0.f);
            Ls[w * 16 + rg0 + rr][dt * 16 + lr] = v;
        }
    }
    __syncthreads();
    int s = tid >> 2, nq = (tid & 3) * 16;
    long go = ((long)i0 + s) * HH + j0 + nq;
    if (outF) {
        #pragma unroll
        for (int q = 0; q < 4; ++q) {
            float4 v = *(float4*)&Ls[s][nq + q * 4];
            if (res) {
                float4 r = *(const float4*)&res[go + q * 4];
                v.x += r.x; v.y += r.y; v.z += r.z; v.w += r.w;
            }
            *(float4*)&outF[go + q * 4] = v;
        }
    } else {
        float v0[8], v1[8];
        #pragma unroll
        for (int e = 0; e < 8; ++e) { v0[e] = Ls[s][nq + e]; v1[e] = Ls[s][nq + 8 + e]; }
        half8 h0, l0, h1, l1; split8(v0, h0, l0); split8(v1, h1, l1);
        *(half8*)&outH[go] = h0; *(half8*)&outH[go + 8] = h1;
        *(half8*)&outL[go] = l0; *(half8*)&outL[go + 8] = l1;
    }
}

extern "C" void kernel_launch(void* const* d_in, const int* in_sizes, int n_in,
                              void* d_out, int out_size, void* d_ws, size_t ws_size,
                              hipStream_t stream)
{
    const float* inputs = (const float*)d_in[0];
    const float* graphs = (const float*)d_in[1];
    const float* biases = (const float*)d_in[2];
    const float* gc_w   = (const float*)d_in[3];
    const float* gc_b   = (const float*)d_in[4];
    const float* attn_w = (const float*)d_in[5];
    const float* attn_a = (const float*)d_in[6];
    const float* ln_a   = (const float*)d_in[7];
    const float* ln_b   = (const float*)d_in[8];
    const float* w1     = (const float*)d_in[9];
    const float* w1b    = (const float*)d_in[10];
    const float* w2     = (const float*)d_in[11];
    const float* w2b    = (const float*)d_in[12];
    float* out = (float*)d_out;

    // ---- workspace layout (float offsets), ~55 MB total ----
    float* ws   = (float*)d_ws;
    float* X    = ws;                     // 2,097,152
    float* G    = ws + 2097152;           // 2,097,152
    float* PTS  = ws + 4194304;           // 2,097,152 (NPART*BB*SS)
    float* F    = ws + 6291456;           // 8,192
    float* Mv   = ws + 6299648;           // 8,192
    float2* FC  = (float2*)(ws + 6307840);// 16,384 (float2 per b,j)
    float* by   = ws + 6324224;           // 128
    int*   FMXi = (int*)(ws + 6324352);   // 8 (pad 128)
    f16* WysH   = (f16*)(ws + 6324480);   // 32,768 halves
    f16* WysL   = (f16*)(ws + 6340864);
    f16* yTh    = (f16*)(ws + 6357248);   // 524,288 halves each
    f16* yTl    = (f16*)(ws + 6619392);
    f16* fTh    = (f16*)(ws + 6881536);
    f16* fTl    = (f16*)(ws + 7143680);
    f16* xh     = (f16*)(ws + 7405824);   // 2,097,152 halves each
    f16* xl     = (f16*)(ws + 8454400);
    f16* gh     = (f16*)(ws + 9502976);
    f16* gl     = (f16*)(ws + 10551552);
    f16* h1h    = (f16*)(ws + 11600128);
    f16* h1l    = (f16*)(ws + 12648704);
    f16* w1h    = (f16*)(ws + 13697280);  // 65,536 halves each
    f16* w1l    = (f16*)(ws + 13730048);
    f16* w2h    = (f16*)(ws + 13762816);
    f16* w2l    = (f16*)(ws + 13795584);  // end 13,828,352 floats

    const float* adjBase  = graphs + (long)SS * SS;  // [:, TYPE_IDX=1]
    const float* biasBase = biases + (long)SS * SS;

    prep_all<<<1152, 256, 0, stream>>>(gc_w, gc_b, attn_w, WysH, WysL, by,
                                       w1, w2, w1h, w1l, w2h, w2l, FMXi,
                                       inputs, xh, xl);

    for (int L = 0; L < NLAYERS; ++L) {
        y_mfma<<<128, 256, 0, stream>>>(xh, xl,
            WysH + (long)L * DD * HH, WysL + (long)L * DD * HH, yTh, yTl);
        ftp_fused<<<dim3(128, BB), 512, 0, stream>>>(
            adjBase, yTh, yTl, by + L * DD, attn_a + (long)L * DD,
            F, fTh, fTl, FMXi + L * BB);
        col_stats_part<<<dim3(2, 128, BB), 512, 0, stream>>>(
            biasBase, F, FMXi + L * BB, PTS, Mv);
        col_stats_merge<<<dim3(32, BB), 256, 0, stream>>>(PTS, Mv, F, FC);
        pvp_fused<<<dim3(128, BB), 512, 0, stream>>>(
            biasBase, F, FC, fTh, fTl,
            (L == 0) ? inputs : X, X, xh, xl, (L == 0) ? 1 : 0);
    }

    layernorm_g<<<2048, 256, 0, stream>>>(X, inputs, ln_a, ln_b, G, gh, gl);
    ffn_mfma<<<dim3(128, 4), 256, 0, stream>>>(gh, gl, w1h, w1l, w1b,
                                               nullptr, nullptr, h1h, h1l, 1);
    ffn_mfma<<<dim3(128, 4), 256, 0, stream>>>(h1h, h1l, w2h, w2l, w2b,
                                               G, out, nullptr, nullptr, 0);
}

// Round 11
// 298.559 us; speedup vs baseline: 1.1290x; 1.1290x over previous
//
#include <hip/hip_runtime.h>
#include <math.h>

#define BB 4
#define SS 2048
#define HH 256
#define DD 64
#define NLAYERS 2
#define NPART 128     // i-partials for column stats (64 chunks x 2 halves)

// static scales for f16 hi/lo splits (layer-2 activations are large)
#define XSC  (1.f/64.f)   // x stored as x/64
#define XSCI 64.f
#define FSC  (1.f/256.f)  // ft stored as ft/256
#define WSC  256.f        // W stored as 256*W (256 * 1/256 = 1 in product)
#define LNWSC 5.5451774444795624f   // ln(256)
#define EC1  190781.31f   // 64 * e^8 : E' = exp(l-M)*EC1 = exp(l-P)*64
#define CWC  1.3418535e-3f // WSC / EC1

typedef _Float16 f16;
typedef f16 half8 __attribute__((ext_vector_type(8)));
typedef f16 half4 __attribute__((ext_vector_type(4)));
typedef float f32x4 __attribute__((ext_vector_type(4)));
#define MFMA16(a, b, c) __builtin_amdgcn_mfma_f32_16x16x32_f16(a, b, c, 0, 0, 0)

__device__ __forceinline__ float lrelu(float v) { return v > 0.f ? v : 0.01f * v; }
__device__ __forceinline__ int enc(float f) { int i = __float_as_int(f); return i >= 0 ? i : (i ^ 0x7fffffff); }
__device__ __forceinline__ float dec(int k) { int i = k >= 0 ? k : (k ^ 0x7fffffff); return __int_as_float(i); }
__device__ __forceinline__ void split8(const float* v, half8& h, half8& l) {
    #pragma unroll
    for (int e = 0; e < 8; ++e) {
        f16 hh = (f16)v[e]; h[e] = hh; l[e] = (f16)((v[e] - (float)hh) * 2048.f);
    }
}

// blocks 0-127: Wy = gc_w@attn_w^T split, by, w1/w2 splits, FMX init
// blocks 128-1151: inputs*XSC -> xh/xl split
__global__ __launch_bounds__(256) void prep_all(
    const float* __restrict__ gc_w, const float* __restrict__ gc_b,
    const float* __restrict__ attn_w,
    f16* __restrict__ WysH, f16* __restrict__ WysL, float* __restrict__ by,
    const float* __restrict__ w1, const float* __restrict__ w2,
    f16* __restrict__ w1h, f16* __restrict__ w1l,
    f16* __restrict__ w2h, f16* __restrict__ w2l, int* __restrict__ FMXi,
    const float* __restrict__ inputs, f16* __restrict__ xh, f16* __restrict__ xl)
{
    if (blockIdx.x >= 128) {
        long i = ((long)(blockIdx.x - 128) * 256 + threadIdx.x) * 8;
        float4 a = *(const float4*)&inputs[i];
        float4 b = *(const float4*)&inputs[i + 4];
        float v[8] = {a.x * XSC, a.y * XSC, a.z * XSC, a.w * XSC,
                      b.x * XSC, b.y * XSC, b.z * XSC, b.w * XSC};
        half8 h, l; split8(v, h, l);
        *(half8*)&xh[i] = h; *(half8*)&xl[i] = l;
        return;
    }
    int L = blockIdx.x >> 6, d = blockIdx.x & 63;
    int h = threadIdx.x;
    const float* gwr = gc_w + (long)L * HH * HH + (long)h * HH;
    const float* aw = attn_w + (long)L * DD * HH + (long)d * HH;
    float acc = 0.f;
    #pragma unroll 4
    for (int hp = 0; hp < HH; hp += 4) {
        float4 g4 = *(const float4*)&gwr[hp];
        float4 a4 = *(const float4*)&aw[hp];
        acc += g4.x * a4.x + g4.y * a4.y + g4.z * a4.z + g4.w * a4.w;
    }
    f16 hh = (f16)acc;
    WysH[((long)L * DD + d) * HH + h] = hh;
    WysL[((long)L * DD + d) * HH + h] = (f16)((acc - (float)hh) * 2048.f);
    if (h == 0) {
        float ba = 0.f;
        const float* gb = gc_b + (long)L * HH;
        for (int hp = 0; hp < HH; ++hp) ba += gb[hp] * aw[hp];
        by[L * DD + d] = ba;
    }
    int gt = blockIdx.x * 256 + h;   // 32768 threads x 4 = 131072 = 2*65536
    #pragma unroll
    for (int p = 0; p < 4; ++p) {
        int e = gt * 4 + p;
        if (e < 65536) {
            float v = w1[e]; f16 x = (f16)v;
            w1h[e] = x; w1l[e] = (f16)((v - (float)x) * 2048.f);
        } else {
            int e2 = e - 65536;
            float v = w2[e2]; f16 x = (f16)v;
            w2h[e2] = x; w2l[e2] = (f16)((v - (float)x) * 2048.f);
        }
    }
    if (blockIdx.x == 0 && h < 2 * BB) FMXi[h] = enc(-1e30f);
}

// yT[b][d][s] (split of y/64) = (x/64) @ Wy  (4 waves/block, wave = 16 rows)
__global__ __launch_bounds__(256) void y_mfma(
    const f16* __restrict__ xh, const f16* __restrict__ xl,
    const f16* __restrict__ WyhL, const f16* __restrict__ WylL,
    f16* __restrict__ yTh, f16* __restrict__ yTl)
{
    const int tid = threadIdx.x;
    const int w = tid >> 6, l = tid & 63;
    const int gw = blockIdx.x * 4 + w;   // global wave: b*128 + st
    const int b = gw >> 7, st = gw & 127;
    const int s0 = st * 16;
    const int lr = l & 15, kg = (l >> 4) * 8;
    const f16* Aph = xh + ((long)b * SS + s0 + lr) * HH;
    const f16* Apl = xl + ((long)b * SS + s0 + lr) * HH;
    f32x4 acch[4] = {}, accm[4] = {};
    #pragma unroll
    for (int k0 = 0; k0 < HH; k0 += 32) {
        half8 ah = *(const half8*)(Aph + k0 + kg);
        half8 al = *(const half8*)(Apl + k0 + kg);
        #pragma unroll
        for (int dt = 0; dt < 4; ++dt) {
            long boff = (long)(dt * 16 + lr) * HH + k0 + kg;
            half8 bh = *(const half8*)(WyhL + boff);
            half8 bl = *(const half8*)(WylL + boff);
            acch[dt] = MFMA16(ah, bh, acch[dt]);
            accm[dt] = MFMA16(ah, bl, accm[dt]);
            accm[dt] = MFMA16(al, bh, accm[dt]);
        }
    }
    const int rg0 = (l >> 4) * 4;
    #pragma unroll
    for (int dt = 0; dt < 4; ++dt) {
        int d = dt * 16 + lr;
        half4 h4, l4;
        #pragma unroll
        for (int rr = 0; rr < 4; ++rr) {
            float v = acch[dt][rr] + accm[dt][rr] * (1.f / 2048.f);
            f16 hh = (f16)v; h4[rr] = hh; l4[rr] = (f16)((v - (float)hh) * 2048.f);
        }
        long ob = ((long)b * DD + d) * SS + s0 + rg0;
        *(half4*)(yTh + ob) = h4;
        *(half4*)(yTl + ob) = l4;
    }
}

// ft tile [16 x 64] = adj[i0..i0+16, :] @ y  (8 waves x 256-k slices, full K)
// epilogue: F = ft@attn_a, atomic fmax, fT split write.
__global__ __launch_bounds__(512, 2) void ftp_fused(
    const float* __restrict__ adjB,
    const f16* __restrict__ yTh, const f16* __restrict__ yTl,
    const float* __restrict__ byL, const float* __restrict__ aaL,
    float* __restrict__ F, f16* __restrict__ fTh, f16* __restrict__ fTl,
    int* __restrict__ fmxSlot)
{
    __shared__ float Ls[8][16][68];
    __shared__ float fmaxS[16];
    const int b = blockIdx.y;
    const int i0 = blockIdx.x * 16;
    const int tid = threadIdx.x;
    const int w = tid >> 6, l = tid & 63, lr = l & 15, kg = (l >> 4) * 8;
    const float* Arow = adjB + (long)b * 2 * SS * SS + (long)(i0 + lr) * SS;
    const f16* Bh = yTh + ((long)b * DD + lr) * SS;
    const f16* Bl = yTl + ((long)b * DD + lr) * SS;

    f32x4 acch[4] = {}, accm[4] = {};
    #pragma unroll
    for (int ks = 0; ks < 256; ks += 32) {
        int k = w * 256 + ks + kg;
        float4 a0 = *(const float4*)(Arow + k);
        float4 a1 = *(const float4*)(Arow + k + 4);
        float av[8] = {a0.x, a0.y, a0.z, a0.w, a1.x, a1.y, a1.z, a1.w};
        half8 ah, al; split8(av, ah, al);
        #pragma unroll
        for (int dt = 0; dt < 4; ++dt) {
            long off = (long)dt * 16 * SS + k;
            half8 bh = *(const half8*)(Bh + off);
            half8 bl = *(const half8*)(Bl + off);
            acch[dt] = MFMA16(ah, bh, acch[dt]);
            accm[dt] = MFMA16(ah, bl, accm[dt]);
            accm[dt] = MFMA16(al, bh, accm[dt]);
        }
    }
    const int rg0 = (l >> 4) * 4;
    #pragma unroll
    for (int dt = 0; dt < 4; ++dt)
        #pragma unroll
        for (int rr = 0; rr < 4; ++rr)
            Ls[w][rg0 + rr][dt * 16 + lr] = acch[dt][rr] + accm[dt][rr] * (1.f / 2048.f);
    __syncthreads();

    // 8-way cross-wave reduce (x64 rescale + by), F-dot, fmax
    {
        int r = tid >> 5, q = tid & 31, c0 = q * 2;
        float s0 = 0.f, s1 = 0.f;
        #pragma unroll
        for (int ww = 0; ww < 8; ++ww) { s0 += Ls[ww][r][c0]; s1 += Ls[ww][r][c0 + 1]; }
        s0 = s0 * XSCI + byL[c0];
        s1 = s1 * XSCI + byL[c0 + 1];
        Ls[0][r][c0] = s0; Ls[0][r][c0 + 1] = s1;
        float dot = s0 * aaL[c0] + s1 * aaL[c0 + 1];
        dot += __shfl_xor(dot, 1, 64);
        dot += __shfl_xor(dot, 2, 64);
        dot += __shfl_xor(dot, 4, 64);
        dot += __shfl_xor(dot, 8, 64);
        dot += __shfl_xor(dot, 16, 64);
        if (q == 0) { F[b * SS + i0 + r] = dot; fmaxS[r] = dot; }
    }
    __syncthreads();
    if (tid == 0) {
        float m = -1e30f;
        #pragma unroll
        for (int r = 0; r < 16; ++r) m = fmaxf(m, fmaxS[r]);
        atomicMax(fmxSlot + b, enc(m));
    }
    // transposed split write of ft*FSC (first 256 threads)
    if (tid < 256) {
        int d = tid >> 2, sq = (tid & 3) * 4;
        half4 h4, l4;
        #pragma unroll
        for (int e = 0; e < 4; ++e) {
            float v = Ls[0][sq + e][d] * FSC;
            f16 hh = (f16)v; h4[e] = hh; l4[e] = (f16)((v - (float)hh) * 2048.f);
        }
        long ob = ((long)b * DD + d) * SS + i0 + sq;
        *(half4*)(fTh + ob) = h4;
        *(half4*)(fTl + ob) = l4;
    }
}

// Column softmax partial sums, bound M_j = lrelu(fmax_b + f_j) + 8.
// 512 threads: half = tid>>8 covers 16 rows; thread = 4 j. 8 iters.
// Optionally stores E' = exp(l - M_j)*EC1 as f16 (U-cache for layer-2 pvp).
__global__ __launch_bounds__(512) void col_stats_part(
    const float* __restrict__ biasb, const float* __restrict__ f,
    const int* __restrict__ fmxSlot,
    float* __restrict__ partS, float* __restrict__ Mv, f16* __restrict__ EhL)
{
    __shared__ float fs[32];
    const int b = blockIdx.z;
    const int chunk = blockIdx.y;          // 0..63, 32 rows each
    const int half = threadIdx.x >> 8;     // 0/1 -> 16 rows each
    const int t = threadIdx.x & 255;
    const int j0 = blockIdx.x * 1024 + t * 4;
    const float* bb = biasb + (long)b * 2 * SS * SS;
    const int ibase = chunk * 32 + half * 16;

    if (threadIdx.x < 32) fs[threadIdx.x] = f[b * SS + chunk * 32 + threadIdx.x];

    float fj[4], M[4], s[4] = {0.f, 0.f, 0.f, 0.f};
    const float fmx = dec(fmxSlot[b]);
    #pragma unroll
    for (int q = 0; q < 4; ++q) {
        fj[q] = f[b * SS + j0 + q];
        M[q] = lrelu(fmx + fj[q]) + 8.f;
    }
    __syncthreads();

    #pragma unroll
    for (int ii = 0; ii < 16; ii += 2) {
        float fi0 = fs[half * 16 + ii], fi1 = fs[half * 16 + ii + 1];
        float4 b0 = *(const float4*)&bb[(long)(ibase + ii) * SS + j0];
        float4 b1 = *(const float4*)&bb[(long)(ibase + ii + 1) * SS + j0];
        float e00 = __expf(lrelu(fi0 + fj[0]) + b0.x - M[0]);
        float e01 = __expf(lrelu(fi0 + fj[1]) + b0.y - M[1]);
        float e02 = __expf(lrelu(fi0 + fj[2]) + b0.z - M[2]);
        float e03 = __expf(lrelu(fi0 + fj[3]) + b0.w - M[3]);
        float e10 = __expf(lrelu(fi1 + fj[0]) + b1.x - M[0]);
        float e11 = __expf(lrelu(fi1 + fj[1]) + b1.y - M[1]);
        float e12 = __expf(lrelu(fi1 + fj[2]) + b1.z - M[2]);
        float e13 = __expf(lrelu(fi1 + fj[3]) + b1.w - M[3]);
        s[0] += e00 + e10; s[1] += e01 + e11;
        s[2] += e02 + e12; s[3] += e03 + e13;
        if (EhL) {
            half4 h0, h1;
            h0[0] = (f16)(e00 * EC1); h0[1] = (f16)(e01 * EC1);
            h0[2] = (f16)(e02 * EC1); h0[3] = (f16)(e03 * EC1);
            h1[0] = (f16)(e10 * EC1); h1[1] = (f16)(e11 * EC1);
            h1[2] = (f16)(e12 * EC1); h1[3] = (f16)(e13 * EC1);
            *(half4*)&EhL[((long)b * SS + ibase + ii) * SS + j0] = h0;
            *(half4*)&EhL[((long)b * SS + ibase + ii + 1) * SS + j0] = h1;
        }
    }
    const int c = chunk * 2 + half;        // 0..127
    #pragma unroll
    for (int q = 0; q < 4; ++q)
        partS[((long)c * BB + b) * SS + j0 + q] = s[q];
    if (c == 0) {
        #pragma unroll
        for (int q = 0; q < 4; ++q) Mv[b * SS + j0 + q] = M[q];
    }
}

// Cv[b,j] = ln(WSC) - ln(S) - M_j  (layer-1 pvp);  Cw[b,j] = CWC / S (layer-2)
__global__ __launch_bounds__(256) void col_stats_merge(
    const float* __restrict__ partS, const float* __restrict__ Mv,
    float* __restrict__ Cv, float* __restrict__ Cw)
{
    __shared__ float red[4][64];
    const int b = blockIdx.y;
    const int jl = threadIdx.x & 63;
    const int p = threadIdx.x >> 6;
    const int j = blockIdx.x * 64 + jl;
    float s = 0.f;
    #pragma unroll
    for (int k = 0; k < 32; ++k)
        s += partS[((long)(p * 32 + k) * BB + b) * SS + j];
    red[p][jl] = s;
    __syncthreads();
    if (p == 0) {
        float tot = ((red[0][jl] + red[1][jl]) + (red[2][jl] + red[3][jl]));
        Cv[b * SS + j] = LNWSC - __logf(tot) - Mv[b * SS + j];
        Cw[b * SS + j] = CWC / tot;
    }
}

// LAYER-1 pvp: ret tile [16x64] = coefs @ ft. W*WSC = exp(lrelu(fi+fj)+bias+Cj).
// Epilogue: lrelu + tile + residual -> X (+ x/64 split for next layer).
__global__ __launch_bounds__(512, 2) void pvp_fused(
    const float* __restrict__ biasb, const float* __restrict__ f,
    const float* __restrict__ Cv,
    const f16* __restrict__ fTh, const f16* __restrict__ fTl,
    const float* __restrict__ xin, float* __restrict__ X,
    f16* __restrict__ xh, f16* __restrict__ xl)
{
    __shared__ float Ls[8][16][68];
    const int b = blockIdx.y;
    const int i0 = blockIdx.x * 16;
    const int tid = threadIdx.x;
    const int w = tid >> 6, l = tid & 63, lr = l & 15, kg = (l >> 4) * 8;
    const int irow = i0 + lr;
    const float fi = f[b * SS + irow];
    const float* brow = biasb + (long)b * 2 * SS * SS + (long)irow * SS;
    const float* fb = f + b * SS;
    const float* cb = Cv + b * SS;
    const f16* Bh = fTh + ((long)b * DD + lr) * SS;
    const f16* Bl = fTl + ((long)b * DD + lr) * SS;

    f32x4 acch[4] = {}, accm[4] = {};
    #pragma unroll
    for (int jc = 0; jc < 256; jc += 32) {
        const int jb = w * 256 + jc + kg;
        float4 bs0 = *(const float4*)(brow + jb);
        float4 bs1 = *(const float4*)(brow + jb + 4);
        float4 fj0 = *(const float4*)(fb + jb);
        float4 fj1 = *(const float4*)(fb + jb + 4);
        float4 cj0 = *(const float4*)(cb + jb);
        float4 cj1 = *(const float4*)(cb + jb + 4);
        float wv[8];
        wv[0] = __expf(lrelu(fi + fj0.x) + bs0.x + cj0.x);
        wv[1] = __expf(lrelu(fi + fj0.y) + bs0.y + cj0.y);
        wv[2] = __expf(lrelu(fi + fj0.z) + bs0.z + cj0.z);
        wv[3] = __expf(lrelu(fi + fj0.w) + bs0.w + cj0.w);
        wv[4] = __expf(lrelu(fi + fj1.x) + bs1.x + cj1.x);
        wv[5] = __expf(lrelu(fi + fj1.y) + bs1.y + cj1.y);
        wv[6] = __expf(lrelu(fi + fj1.z) + bs1.z + cj1.z);
        wv[7] = __expf(lrelu(fi + fj1.w) + bs1.w + cj1.w);
        half8 ah, al; split8(wv, ah, al);
        #pragma unroll
        for (int dt = 0; dt < 4; ++dt) {
            long off = (long)dt * 16 * SS + jb;
            half8 bh = *(const half8*)(Bh + off);
            half8 bl = *(const half8*)(Bl + off);
            acch[dt] = MFMA16(ah, bh, acch[dt]);
            accm[dt] = MFMA16(ah, bl, accm[dt]);
            accm[dt] = MFMA16(al, bh, accm[dt]);
        }
    }
    const int rg0 = (l >> 4) * 4;
    #pragma unroll
    for (int dt = 0; dt < 4; ++dt)
        #pragma unroll
        for (int rr = 0; rr < 4; ++rr)
            Ls[w][rg0 + rr][dt * 16 + lr] = acch[dt][rr] + accm[dt][rr] * (1.f / 2048.f);
    __syncthreads();

    {
        int r = tid >> 5, q = tid & 31, dq = q * 2;
        float v0 = 0.f, v1 = 0.f;
        #pragma unroll
        for (int ww = 0; ww < 8; ++ww) { v0 += Ls[ww][r][dq]; v1 += Ls[ww][r][dq + 1]; }
        v0 = lrelu(v0); v1 = lrelu(v1);
        long rowoff = ((long)b * SS + i0 + r) * HH;
        #pragma unroll
        for (int rep = 0; rep < 4; ++rep) {
            long off = rowoff + rep * DD + dq;
            float o0 = v0 + xin[off];
            float o1 = v1 + xin[off + 1];
            X[off] = o0; X[off + 1] = o1;
            float s0 = o0 * XSC, s1 = o1 * XSC;
            f16 h0 = (f16)s0, h1 = (f16)s1;
            xh[off] = h0; xl[off] = (f16)((s0 - (float)h0) * 2048.f);
            xh[off + 1] = h1; xl[off + 1] = (f16)((s1 - (float)h1) * 2048.f);
        }
    }
}

// LAYER-2 pvp (U-cache): W*WSC = E'[i][j] * Cw[j]. No bias/exp in the loop.
__global__ __launch_bounds__(512, 2) void pvp_fused2(
    const f16* __restrict__ Eh, const float* __restrict__ Cw,
    const f16* __restrict__ fTh, const f16* __restrict__ fTl,
    const float* __restrict__ xin, float* __restrict__ X)
{
    __shared__ float Ls[8][16][68];
    const int b = blockIdx.y;
    const int i0 = blockIdx.x * 16;
    const int tid = threadIdx.x;
    const int w = tid >> 6, l = tid & 63, lr = l & 15, kg = (l >> 4) * 8;
    const int irow = i0 + lr;
    const f16* Erow = Eh + ((long)b * SS + irow) * SS;
    const float* cw = Cw + (long)b * SS;
    const f16* Bh = fTh + ((long)b * DD + lr) * SS;
    const f16* Bl = fTl + ((long)b * DD + lr) * SS;

    f32x4 acch[4] = {}, accm[4] = {};
    #pragma unroll
    for (int jc = 0; jc < 256; jc += 32) {
        const int jb = w * 256 + jc + kg;
        half8 ev = *(const half8*)(Erow + jb);
        float4 c0 = *(const float4*)(cw + jb);
        float4 c1 = *(const float4*)(cw + jb + 4);
        float wv[8];
        wv[0] = (float)ev[0] * c0.x; wv[1] = (float)ev[1] * c0.y;
        wv[2] = (float)ev[2] * c0.z; wv[3] = (float)ev[3] * c0.w;
        wv[4] = (float)ev[4] * c1.x; wv[5] = (float)ev[5] * c1.y;
        wv[6] = (float)ev[6] * c1.z; wv[7] = (float)ev[7] * c1.w;
        half8 ah, al; split8(wv, ah, al);
        #pragma unroll
        for (int dt = 0; dt < 4; ++dt) {
            long off = (long)dt * 16 * SS + jb;
            half8 bh = *(const half8*)(Bh + off);
            half8 bl = *(const half8*)(Bl + off);
            acch[dt] = MFMA16(ah, bh, acch[dt]);
            accm[dt] = MFMA16(ah, bl, accm[dt]);
            accm[dt] = MFMA16(al, bh, accm[dt]);
        }
    }
    const int rg0 = (l >> 4) * 4;
    #pragma unroll
    for (int dt = 0; dt < 4; ++dt)
        #pragma unroll
        for (int rr = 0; rr < 4; ++rr)
            Ls[w][rg0 + rr][dt * 16 + lr] = acch[dt][rr] + accm[dt][rr] * (1.f / 2048.f);
    __syncthreads();

    {
        int r = tid >> 5, q = tid & 31, dq = q * 2;
        float v0 = 0.f, v1 = 0.f;
        #pragma unroll
        for (int ww = 0; ww < 8; ++ww) { v0 += Ls[ww][r][dq]; v1 += Ls[ww][r][dq + 1]; }
        v0 = lrelu(v0); v1 = lrelu(v1);
        long rowoff = ((long)b * SS + i0 + r) * HH;
        #pragma unroll
        for (int rep = 0; rep < 4; ++rep) {
            long off = rowoff + rep * DD + dq;
            X[off] = v0 + xin[off];
            X[off + 1] = v1 + xin[off + 1];
        }
    }
}

// g = ln_a*(x-mean)/(std+eps) + ln_b + x0 ; wave-per-row, float4 per lane
__global__ __launch_bounds__(256) void layernorm_g(
    const float* __restrict__ x, const float* __restrict__ x0,
    const float* __restrict__ lna, const float* __restrict__ lnb,
    float* __restrict__ g, f16* __restrict__ gh, f16* __restrict__ gl)
{
    const int wave = threadIdx.x >> 6, lane = threadIdx.x & 63;
    const long row = (long)blockIdx.x * 4 + wave;
    const int c0 = lane * 4;
    float4 v = *(const float4*)&x[row * HH + c0];
    float s = v.x + v.y + v.z + v.w;
    #pragma unroll
    for (int off = 32; off; off >>= 1) s += __shfl_xor(s, off, 64);
    float mean = s * (1.f / HH);
    float dx = v.x - mean, dy = v.y - mean, dz = v.z - mean, dw = v.w - mean;
    float sq = dx * dx + dy * dy + dz * dz + dw * dw;
    #pragma unroll
    for (int off = 32; off; off >>= 1) sq += __shfl_xor(sq, off, 64);
    float stdv = sqrtf(sq * (1.f / (HH - 1)));
    float rinv = 1.f / (stdv + 1e-6f);
    float4 la = *(const float4*)&lna[c0];
    float4 lb = *(const float4*)&lnb[c0];
    float4 xo = *(const float4*)&x0[row * HH + c0];
    float gv[4];
    gv[0] = la.x * dx * rinv + lb.x + xo.x;
    gv[1] = la.y * dy * rinv + lb.y + xo.y;
    gv[2] = la.z * dz * rinv + lb.z + xo.z;
    gv[3] = la.w * dw * rinv + lb.w + xo.w;
    *(float4*)&g[row * HH + c0] = *(float4*)gv;
    half4 h4, l4;
    #pragma unroll
    for (int e = 0; e < 4; ++e) {
        f16 hh = (f16)gv[e]; h4[e] = hh; l4[e] = (f16)((gv[e] - (float)hh) * 2048.f);
    }
    *(half4*)&gh[row * HH + c0] = h4;
    *(half4*)&gl[row * HH + c0] = l4;
}

// C = A@B^T (+bias)(relu)(+res). A split [M][256]; B split [256][256] (row=n).
__global__ __launch_bounds__(256) void ffn_mfma(
    const f16* __restrict__ Ah, const f16* __restrict__ Al,
    const f16* __restrict__ Bh, const f16* __restrict__ Bl,
    const float* __restrict__ bias, const float* __restrict__ res,
    float* __restrict__ outF, f16* __restrict__ outH, f16* __restrict__ outL,
    int doRelu)
{
    __shared__ float Ls[64][68];
    const int i0 = blockIdx.x * 64, j0 = blockIdx.y * 64;
    const int tid = threadIdx.x;
    const int w = tid >> 6, l = tid & 63, lr = l & 15, kg = (l >> 4) * 8;
    const f16* Aph = Ah + ((long)i0 + w * 16 + lr) * HH;
    const f16* Apl = Al + ((long)i0 + w * 16 + lr) * HH;
    f32x4 acch[4] = {}, accm[4] = {};
    #pragma unroll
    for (int k0 = 0; k0 < HH; k0 += 32) {
        half8 ah = *(const half8*)(Aph + k0 + kg);
        half8 al = *(const half8*)(Apl + k0 + kg);
        #pragma unroll
        for (int dt = 0; dt < 4; ++dt) {
            long boff = ((long)(j0 + dt * 16 + lr)) * HH + k0 + kg;
            half8 bh = *(const half8*)(Bh + boff);
            half8 bl = *(const half8*)(Bl + boff);
            acch[dt] = MFMA16(ah, bh, acch[dt]);
            accm[dt] = MFMA16(ah, bl, accm[dt]);
            accm[dt] = MFMA16(al, bh, accm[dt]);
        }
    }
    const int rg0 = (l >> 4) * 4;
    #pragma unroll
    for (int dt = 0; dt < 4; ++dt) {
        float bj = bias[j0 + dt * 16 + lr];
        #pragma unroll
        for (int rr = 0; rr < 4; ++rr) {
            float v = acch[dt][rr] + accm[dt][rr] * (1.f / 2048.f) + bj;
            if (doRelu) v = fmaxf(v, 0.f);
            Ls[w * 16 + rg0 + rr][dt * 16 + lr] = v;
        }
    }
    __syncthreads();
    int s = tid >> 2, nq = (tid & 3) * 16;
    long go = ((long)i0 + s) * HH + j0 + nq;
    if (outF) {
        #pragma unroll
        for (int q = 0; q < 4; ++q) {
            float4 v = *(float4*)&Ls[s][nq + q * 4];
            if (res) {
                float4 r = *(const float4*)&res[go + q * 4];
                v.x += r.x; v.y += r.y; v.z += r.z; v.w += r.w;
            }
            *(float4*)&outF[go + q * 4] = v;
        }
    } else {
        float v0[8], v1[8];
        #pragma unroll
        for (int e = 0; e < 8; ++e) { v0[e] = Ls[s][nq + e]; v1[e] = Ls[s][nq + 8 + e]; }
        half8 h0, l0, h1, l1; split8(v0, h0, l0); split8(v1, h1, l1);
        *(half8*)&outH[go] = h0; *(half8*)&outH[go + 8] = h1;
        *(half8*)&outL[go] = l0; *(half8*)&outL[go + 8] = l1;
    }
}

extern "C" void kernel_launch(void* const* d_in, const int* in_sizes, int n_in,
                              void* d_out, int out_size, void* d_ws, size_t ws_size,
                              hipStream_t stream)
{
    const float* inputs = (const float*)d_in[0];
    const float* graphs = (const float*)d_in[1];
    const float* biases = (const float*)d_in[2];
    const float* gc_w   = (const float*)d_in[3];
    const float* gc_b   = (const float*)d_in[4];
    const float* attn_w = (const float*)d_in[5];
    const float* attn_a = (const float*)d_in[6];
    const float* ln_a   = (const float*)d_in[7];
    const float* ln_b   = (const float*)d_in[8];
    const float* w1     = (const float*)d_in[9];
    const float* w1b    = (const float*)d_in[10];
    const float* w2     = (const float*)d_in[11];
    const float* w2b    = (const float*)d_in[12];
    float* out = (float*)d_out;

    // ---- workspace layout (float offsets), ~85 MB total ----
    float* ws   = (float*)d_ws;
    float* X    = ws;                     // 2,097,152
    float* G    = ws + 2097152;           // 2,097,152
    float* PTS  = ws + 4194304;           // 1,048,576 (NPART*BB*SS)
    float* F    = ws + 5242880;           // 8,192
    float* Mv   = ws + 5251072;           // 8,192
    float* Cv   = ws + 5259264;           // 8,192
    float* Cw   = ws + 5267456;           // 8,192
    float* by   = ws + 5275648;           // 128
    int*   FMXi = (int*)(ws + 5275776);   // 8 (pad 128)
    f16* WysH   = (f16*)(ws + 5275904);   // 32,768 halves
    f16* WysL   = (f16*)(ws + 5292288);
    f16* yTh    = (f16*)(ws + 5308672);   // 524,288 halves each
    f16* yTl    = (f16*)(ws + 5570816);
    f16* fTh    = (f16*)(ws + 5832960);
    f16* fTl    = (f16*)(ws + 6095104);
    f16* xh     = (f16*)(ws + 6357248);   // 2,097,152 halves each
    f16* xl     = (f16*)(ws + 7405824);
    f16* gh     = (f16*)(ws + 8454400);
    f16* gl     = (f16*)(ws + 9502976);
    f16* h1h    = (f16*)(ws + 10551552);
    f16* h1l    = (f16*)(ws + 11600128);
    f16* w1h    = (f16*)(ws + 12648704);  // 65,536 halves each
    f16* w1l    = (f16*)(ws + 12681472);
    f16* w2h    = (f16*)(ws + 12714240);
    f16* w2l    = (f16*)(ws + 12747008);
    f16* Eh     = (f16*)(ws + 12779776);  // 16,777,216 halves = 8,388,608 floats
                                          // end 21,168,384 floats (~85 MB)

    const float* adjBase  = graphs + (long)SS * SS;  // [:, TYPE_IDX=1]
    const float* biasBase = biases + (long)SS * SS;

    prep_all<<<1152, 256, 0, stream>>>(gc_w, gc_b, attn_w, WysH, WysL, by,
                                       w1, w2, w1h, w1l, w2h, w2l, FMXi,
                                       inputs, xh, xl);

    for (int L = 0; L < NLAYERS; ++L) {
        y_mfma<<<128, 256, 0, stream>>>(xh, xl,
            WysH + (long)L * DD * HH, WysL + (long)L * DD * HH, yTh, yTl);
        ftp_fused<<<dim3(128, BB), 512, 0, stream>>>(
            adjBase, yTh, yTl, by + L * DD, attn_a + (long)L * DD,
            F, fTh, fTl, FMXi + L * BB);
        col_stats_part<<<dim3(2, 64, BB), 512, 0, stream>>>(
            biasBase, F, FMXi + L * BB, PTS, Mv, (L == 1) ? Eh : (f16*)nullptr);
        col_stats_merge<<<dim3(32, BB), 256, 0, stream>>>(PTS, Mv, Cv, Cw);
        if (L == 0) {
            pvp_fused<<<dim3(128, BB), 512, 0, stream>>>(
                biasBase, F, Cv, fTh, fTl, inputs, X, xh, xl);
        } else {
            pvp_fused2<<<dim3(128, BB), 512, 0, stream>>>(
                Eh, Cw, fTh, fTl, X, X);
        }
    }

    layernorm_g<<<2048, 256, 0, stream>>>(X, inputs, ln_a, ln_b, G, gh, gl);
    ffn_mfma<<<dim3(128, 4), 256, 0, stream>>>(gh, gl, w1h, w1l, w1b,
                                               nullptr, nullptr, h1h, h1l, 1);
    ffn_mfma<<<dim3(128, 4), 256, 0, stream>>>(h1h, h1l, w2h, w2l, w2b,
                                               G, out, nullptr, nullptr, 0);
}